// Round 1
// baseline (7103.465 us; speedup 1.0000x reference)
//
#include <hip/hip_runtime.h>

typedef short short8 __attribute__((ext_vector_type(8)));
typedef float f32x4 __attribute__((ext_vector_type(4)));
typedef unsigned short us4 __attribute__((ext_vector_type(4)));

#define SQ 512
#define BA 64
#define HD 1024
#define NWG 64
#define FSTR 16   // uints between flag slots (64 B); 256 slots = 16 KB

// ---------- bf16 helpers (round-to-nearest-even) ----------
__device__ __forceinline__ unsigned short f2bf(float f) {
    unsigned u = __float_as_uint(f);
    u += 0x7fffu + ((u >> 16) & 1u);
    return (unsigned short)(u >> 16);
}
__device__ __forceinline__ float bf2f(unsigned short h) {
    return __uint_as_float(((unsigned)h) << 16);
}
__device__ __forceinline__ void waitcnt_vm0() {
    asm volatile("s_waitcnt vmcnt(0)" ::: "memory");
}
// LLC-coherent 16-B fragment load as 2x8-B relaxed agent atomics
__device__ __forceinline__ short8 ld_frag(const unsigned short* p) {
    const unsigned long long* q = (const unsigned long long*)p;
    unsigned long long a = __hip_atomic_load(q,     __ATOMIC_RELAXED, __HIP_MEMORY_SCOPE_AGENT);
    unsigned long long b = __hip_atomic_load(q + 1, __ATOMIC_RELAXED, __HIP_MEMORY_SCOPE_AGENT);
    union { unsigned long long u[2]; short8 v; } cv;
    cv.u[0] = a; cv.u[1] = b;
    return cv.v;
}

// =====================================================================
// Phase A: xw = x @ W_ih^T + bias. Split-bf16, 3 MFMA products.
// Also zero-inits the 256 per-wave epoch flags (block (0,0), 256 thr).
// =====================================================================
__global__ void __launch_bounds__(256) xw_gemm(
    const float* __restrict__ x, const float* __restrict__ Wih,
    const float* __restrict__ bih, const float* __restrict__ bhh,
    float* __restrict__ out, unsigned* __restrict__ flags)
{
    if (blockIdx.x == 0 && blockIdx.y == 0)
        flags[threadIdx.x * FSTR] = 0u;   // 256 threads -> 256 slots

    __shared__ unsigned short Ahi[128][40];
    __shared__ unsigned short Alo[128][40];
    __shared__ unsigned short Bhi[128][40];
    __shared__ unsigned short Blo[128][40];

    const int tid  = threadIdx.x;
    const int lane = tid & 63, wid = tid >> 6;
    const int bx = blockIdx.x, by = blockIdx.y;
    const int wm = (wid & 1) * 64, wn = (wid >> 1) * 64;
    const int rf = lane & 15, bq = lane >> 4, kf = bq * 8;

    f32x4 acc[4][4] = {};

    const int srow = tid >> 3;
    const int scol = (tid & 7) * 4;
    const float* aBase = x   + (size_t)(bx * 128 + srow) * HD + scol;
    const float* bBase = Wih + (size_t)(by * 128 + srow) * HD + scol;

    for (int kc = 0; kc < 32; ++kc) {
        __syncthreads();
        const int ko = kc * 32;
#pragma unroll
        for (int i = 0; i < 4; ++i) {
            const int r = srow + i * 32;
            float4 av = *(const float4*)(aBase + (size_t)(i * 32) * HD + ko);
            float4 bv = *(const float4*)(bBase + (size_t)(i * 32) * HD + ko);
            us4 ah, al, bh, bl;
            ah.x = f2bf(av.x); al.x = f2bf(av.x - bf2f(ah.x));
            ah.y = f2bf(av.y); al.y = f2bf(av.y - bf2f(ah.y));
            ah.z = f2bf(av.z); al.z = f2bf(av.z - bf2f(ah.z));
            ah.w = f2bf(av.w); al.w = f2bf(av.w - bf2f(ah.w));
            bh.x = f2bf(bv.x); bl.x = f2bf(bv.x - bf2f(bh.x));
            bh.y = f2bf(bv.y); bl.y = f2bf(bv.y - bf2f(bh.y));
            bh.z = f2bf(bv.z); bl.z = f2bf(bv.z - bf2f(bh.z));
            bh.w = f2bf(bv.w); bl.w = f2bf(bv.w - bf2f(bh.w));
            *(us4*)&Ahi[r][scol] = ah;
            *(us4*)&Alo[r][scol] = al;
            *(us4*)&Bhi[r][scol] = bh;
            *(us4*)&Blo[r][scol] = bl;
        }
        __syncthreads();

        short8 afh[4], afl[4], bfh[4], bfl[4];
#pragma unroll
        for (int i = 0; i < 4; ++i) {
            afh[i] = *(const short8*)&Ahi[wm + 16 * i + rf][kf];
            afl[i] = *(const short8*)&Alo[wm + 16 * i + rf][kf];
            bfh[i] = *(const short8*)&Bhi[wn + 16 * i + rf][kf];
            bfl[i] = *(const short8*)&Blo[wn + 16 * i + rf][kf];
        }
#pragma unroll
        for (int i = 0; i < 4; ++i)
#pragma unroll
            for (int j = 0; j < 4; ++j) {
                acc[i][j] = __builtin_amdgcn_mfma_f32_16x16x32_bf16(afh[i], bfh[j], acc[i][j], 0, 0, 0);
                acc[i][j] = __builtin_amdgcn_mfma_f32_16x16x32_bf16(afh[i], bfl[j], acc[i][j], 0, 0, 0);
                acc[i][j] = __builtin_amdgcn_mfma_f32_16x16x32_bf16(afl[i], bfh[j], acc[i][j], 0, 0, 0);
            }
    }

#pragma unroll
    for (int j = 0; j < 4; ++j) {
        const int col = by * 128 + wn + 16 * j + rf;
        const float bias = bih[col] + bhh[col];
#pragma unroll
        for (int i = 0; i < 4; ++i) {
            const int row0 = bx * 128 + wm + 16 * i + bq * 4;
#pragma unroll
            for (int r = 0; r < 4; ++r)
                out[(size_t)(row0 + r) * HD + col] = acc[i][j][r] + bias;
        }
    }
}

// =====================================================================
// Phase B: recurrence — per-WAVE dataflow synchronization.
//   Wave (b,w) owns out tile [batch 16w..16w+16) x [cols 16b..16b+16).
//   It depends ONLY on waves (*, w) (same batch slice): 4 independent
//   pipelines, no __syncthreads in the loop.
//   Sync = 256 per-wave epoch flags: producer drains h-stores (vmcnt(0))
//   then STORES step# to its own 64-B slot (no RMW). Consumers spin
//   wave-parallel (lane l watches block 8g+(l&7)), per 128-column group,
//   issuing that group's h-loads immediately -> load latency overlaps
//   flag propagation of later groups.
// =====================================================================
__global__ void __launch_bounds__(256, 1) rnn_recurrence(
    const float* __restrict__ Whh,
    float* __restrict__ io,
    float* __restrict__ hn,
    unsigned short* __restrict__ hbuf,
    unsigned* __restrict__ flags)
{
    __shared__ unsigned short Whi[16][1032];
    __shared__ unsigned short Wlo[16][1032];

    const int tid = threadIdx.x;
    const int bx  = blockIdx.x;
    const int h0  = bx * 16;

    for (int i = tid; i < 16 * 1024; i += 256) {
        const int r = i >> 10, c = i & 1023;
        const float w = Whh[(size_t)(h0 + r) * HD + c];
        const unsigned short hi = f2bf(w);
        Whi[r][c] = hi;
        Wlo[r][c] = f2bf(w - bf2f(hi));
    }
    __syncthreads();   // only block-wide sync: W tiles ready

    const int lane = tid & 63, wid = tid >> 6;
    const int rf = lane & 15, bq = lane >> 4, kf = bq * 8;

    unsigned short* H0 = hbuf;             // buffer parity = producing step & 1
    unsigned short* H1 = hbuf + BA * HD;

    const int brow = wid * 16 + bq * 4;    // first of 4 batch rows this lane owns
    const int col  = h0 + rf;
    const int ab   = wid * 16 + rf;        // A-frag row (batch) for MFMA

    unsigned* myflag = flags + (size_t)(bx * 4 + wid) * FSTR;
    // group g watch slot: block 8g+(lane&7), wave wid
    const unsigned watchbase = (unsigned)((lane & 7) * 4 + wid) * FSTR;

    float v[4];
    unsigned hi4[4];
    float xwv[4];

    // ---- t = 0: h = tanh(xw_0); store to H0; signal epoch 1 ----
#pragma unroll
    for (int r = 0; r < 4; ++r) {
        v[r] = tanhf(io[(size_t)(brow + r) * HD + col]);
        hi4[r] = f2bf(v[r]);
    }
#pragma unroll
    for (int r = 0; r < 4; ++r) {
        const unsigned oh = __shfl_xor(hi4[r], 1);
        if ((lane & 1) == 0) {
            const size_t e = ((size_t)(brow + r) * HD + col) >> 1;
            __hip_atomic_store((unsigned*)H0 + e, (hi4[r] & 0xffffu) | (oh << 16),
                               __ATOMIC_RELAXED, __HIP_MEMORY_SCOPE_AGENT);
        }
    }
    waitcnt_vm0();
    if (lane == 0)
        __hip_atomic_store(myflag, 1u, __ATOMIC_RELEASE, __HIP_MEMORY_SCOPE_AGENT);

    // prefetch xw[1]
#pragma unroll
    for (int r = 0; r < 4; ++r)
        xwv[r] = io[(size_t)(BA * HD) + (size_t)(brow + r) * HD + col];

    for (int t = 1; t < SQ; ++t) {
        // off-critical-path: store io[t-1] = h_{t-1}; prefetch xw[t+1]
        float* outP = io + (size_t)(t - 1) * (BA * HD);
#pragma unroll
        for (int r = 0; r < 4; ++r)
            outP[(size_t)(brow + r) * HD + col] = v[r];

        float xwn[4] = {0.f, 0.f, 0.f, 0.f};
        if (t + 1 < SQ) {
            const float* nxt = io + (size_t)(t + 1) * (BA * HD);
#pragma unroll
            for (int r = 0; r < 4; ++r)
                xwn[r] = nxt[(size_t)(brow + r) * HD + col];
        }

        const unsigned short* Ph = (t & 1) ? H0 : H1;  // produced at step t-1
        unsigned short*       Nh = (t & 1) ? H1 : H0;  // produced at step t
        const unsigned short* ap = Ph + (size_t)ab * HD + kf;

        // grouped spin + load issue: all 64 A-loads in flight before MFMAs
        short8 a[8][4];
#pragma unroll
        for (int g = 0; g < 8; ++g) {
            const unsigned* fp = flags + watchbase + (unsigned)g * (32u * FSTR);
            unsigned fv = __hip_atomic_load(fp, __ATOMIC_RELAXED, __HIP_MEMORY_SCOPE_AGENT);
            while (!__all((int)(fv >= (unsigned)t)))
                fv = __hip_atomic_load(fp, __ATOMIC_RELAXED, __HIP_MEMORY_SCOPE_AGENT);
#pragma unroll
            for (int i = 0; i < 4; ++i)
                a[g][i] = ld_frag(ap + (size_t)(g * 4 + i) * 32);
        }

        // 4 independent accumulator chains (hi/lo x even/odd kc)
        f32x4 ah0 = {}, ah1 = {}, al0 = {}, al1 = {};
#pragma unroll
        for (int g = 0; g < 8; ++g) {
#pragma unroll
            for (int i = 0; i < 4; ++i) {
                const int kc = g * 4 + i;
                short8 bh = *(const short8*)&Whi[rf][kc * 32 + kf];
                short8 bl = *(const short8*)&Wlo[rf][kc * 32 + kf];
                if (i & 1) {
                    ah1 = __builtin_amdgcn_mfma_f32_16x16x32_bf16(a[g][i], bh, ah1, 0, 0, 0);
                    al1 = __builtin_amdgcn_mfma_f32_16x16x32_bf16(a[g][i], bl, al1, 0, 0, 0);
                } else {
                    ah0 = __builtin_amdgcn_mfma_f32_16x16x32_bf16(a[g][i], bh, ah0, 0, 0, 0);
                    al0 = __builtin_amdgcn_mfma_f32_16x16x32_bf16(a[g][i], bl, al0, 0, 0, 0);
                }
            }
        }

#pragma unroll
        for (int r = 0; r < 4; ++r) {
            v[r] = tanhf(((ah0[r] + ah1[r]) + (al0[r] + al1[r])) + xwv[r]);
            hi4[r] = f2bf(v[r]);
            xwv[r] = xwn[r];
        }

        if (t < SQ - 1) {
#pragma unroll
            for (int r = 0; r < 4; ++r) {
                const unsigned oh = __shfl_xor(hi4[r], 1);
                if ((lane & 1) == 0) {
                    const size_t e = ((size_t)(brow + r) * HD + col) >> 1;
                    __hip_atomic_store((unsigned*)Nh + e, (hi4[r] & 0xffffu) | (oh << 16),
                                       __ATOMIC_RELAXED, __HIP_MEMORY_SCOPE_AGENT);
                }
            }
            waitcnt_vm0();   // h-stores globally visible before epoch bump
            if (lane == 0)
                __hip_atomic_store(myflag, (unsigned)(t + 1),
                                   __ATOMIC_RELEASE, __HIP_MEMORY_SCOPE_AGENT);
        }
    }

    // epilogue: io[511] and h_n
    float* outL = io + (size_t)(SQ - 1) * (BA * HD);
#pragma unroll
    for (int r = 0; r < 4; ++r) {
        const size_t o = (size_t)(brow + r) * HD + col;
        outL[o] = v[r];
        hn[o]   = v[r];
    }
}

// =====================================================================
extern "C" void kernel_launch(void* const* d_in, const int* in_sizes, int n_in,
                              void* d_out, int out_size, void* d_ws, size_t ws_size,
                              hipStream_t stream) {
    const float* x   = (const float*)d_in[0];
    const float* Wih = (const float*)d_in[1];
    const float* Whh = (const float*)d_in[2];
    const float* bih = (const float*)d_in[3];
    const float* bhh = (const float*)d_in[4];

    float* io = (float*)d_out;                       // [512][64][1024]
    float* hn = io + (size_t)SQ * BA * HD;           // [1][64][1024]

    unsigned* flags = (unsigned*)d_ws;                             // 256 x 64 B = 16 KB
    unsigned short* hbuf = (unsigned short*)((char*)d_ws + 16384); // 256 KB ping-pong

    hipLaunchKernelGGL(xw_gemm, dim3(256, 8), dim3(256), 0, stream,
                       x, Wih, bih, bhh, io, flags);

    void* args[] = {(void*)&Whh, (void*)&io, (void*)&hn, (void*)&hbuf, (void*)&flags};
    hipLaunchCooperativeKernel((void*)rnn_recurrence, dim3(NWG), dim3(256),
                               args, 0, stream);
}

// Round 2
// 5627.656 us; speedup vs baseline: 1.2622x; 1.2622x over previous
//
#include <hip/hip_runtime.h>

typedef short short8 __attribute__((ext_vector_type(8)));
typedef float f32x4 __attribute__((ext_vector_type(4)));
typedef unsigned short us4 __attribute__((ext_vector_type(4)));

#define SQ 512
#define BA 64
#define HD 1024
#define NWG 64

// ---------- bf16 helpers (round-to-nearest-even) ----------
__device__ __forceinline__ unsigned short f2bf(float f) {
    unsigned u = __float_as_uint(f);
    u += 0x7fffu + ((u >> 16) & 1u);
    return (unsigned short)(u >> 16);
}
__device__ __forceinline__ float bf2f(unsigned short h) {
    return __uint_as_float(((unsigned)h) << 16);
}
__device__ __forceinline__ void waitcnt_vm0() {
    asm volatile("s_waitcnt vmcnt(0)" ::: "memory");
}
// LLC-coherent 16-B fragment load as 2x8-B relaxed agent atomics
__device__ __forceinline__ short8 ld_frag(const unsigned short* p) {
    const unsigned long long* q = (const unsigned long long*)p;
    unsigned long long a = __hip_atomic_load(q,     __ATOMIC_RELAXED, __HIP_MEMORY_SCOPE_AGENT);
    unsigned long long b = __hip_atomic_load(q + 1, __ATOMIC_RELAXED, __HIP_MEMORY_SCOPE_AGENT);
    union { unsigned long long u[2]; short8 v; } cv;
    cv.u[0] = a; cv.u[1] = b;
    return cv.v;
}

// =====================================================================
// Phase A: xw = x @ W_ih^T + bias. Split-bf16, 3 MFMA products.
// Also zero-inits the 256 packed per-wave epoch flags (block (0,0)).
// =====================================================================
__global__ void __launch_bounds__(256) xw_gemm(
    const float* __restrict__ x, const float* __restrict__ Wih,
    const float* __restrict__ bih, const float* __restrict__ bhh,
    float* __restrict__ out, unsigned* __restrict__ flags)
{
    if (blockIdx.x == 0 && blockIdx.y == 0)
        flags[threadIdx.x] = 0u;   // 256 packed slots

    __shared__ unsigned short Ahi[128][40];
    __shared__ unsigned short Alo[128][40];
    __shared__ unsigned short Bhi[128][40];
    __shared__ unsigned short Blo[128][40];

    const int tid  = threadIdx.x;
    const int lane = tid & 63, wid = tid >> 6;
    const int bx = blockIdx.x, by = blockIdx.y;
    const int wm = (wid & 1) * 64, wn = (wid >> 1) * 64;
    const int rf = lane & 15, bq = lane >> 4, kf = bq * 8;

    f32x4 acc[4][4] = {};

    const int srow = tid >> 3;
    const int scol = (tid & 7) * 4;
    const float* aBase = x   + (size_t)(bx * 128 + srow) * HD + scol;
    const float* bBase = Wih + (size_t)(by * 128 + srow) * HD + scol;

    for (int kc = 0; kc < 32; ++kc) {
        __syncthreads();
        const int ko = kc * 32;
#pragma unroll
        for (int i = 0; i < 4; ++i) {
            const int r = srow + i * 32;
            float4 av = *(const float4*)(aBase + (size_t)(i * 32) * HD + ko);
            float4 bv = *(const float4*)(bBase + (size_t)(i * 32) * HD + ko);
            us4 ah, al, bh, bl;
            ah.x = f2bf(av.x); al.x = f2bf(av.x - bf2f(ah.x));
            ah.y = f2bf(av.y); al.y = f2bf(av.y - bf2f(ah.y));
            ah.z = f2bf(av.z); al.z = f2bf(av.z - bf2f(ah.z));
            ah.w = f2bf(av.w); al.w = f2bf(av.w - bf2f(ah.w));
            bh.x = f2bf(bv.x); bl.x = f2bf(bv.x - bf2f(bh.x));
            bh.y = f2bf(bv.y); bl.y = f2bf(bv.y - bf2f(bh.y));
            bh.z = f2bf(bv.z); bl.z = f2bf(bv.z - bf2f(bh.z));
            bh.w = f2bf(bv.w); bl.w = f2bf(bv.w - bf2f(bh.w));
            *(us4*)&Ahi[r][scol] = ah;
            *(us4*)&Alo[r][scol] = al;
            *(us4*)&Bhi[r][scol] = bh;
            *(us4*)&Blo[r][scol] = bl;
        }
        __syncthreads();

        short8 afh[4], afl[4], bfh[4], bfl[4];
#pragma unroll
        for (int i = 0; i < 4; ++i) {
            afh[i] = *(const short8*)&Ahi[wm + 16 * i + rf][kf];
            afl[i] = *(const short8*)&Alo[wm + 16 * i + rf][kf];
            bfh[i] = *(const short8*)&Bhi[wn + 16 * i + rf][kf];
            bfl[i] = *(const short8*)&Blo[wn + 16 * i + rf][kf];
        }
#pragma unroll
        for (int i = 0; i < 4; ++i)
#pragma unroll
            for (int j = 0; j < 4; ++j) {
                acc[i][j] = __builtin_amdgcn_mfma_f32_16x16x32_bf16(afh[i], bfh[j], acc[i][j], 0, 0, 0);
                acc[i][j] = __builtin_amdgcn_mfma_f32_16x16x32_bf16(afh[i], bfl[j], acc[i][j], 0, 0, 0);
                acc[i][j] = __builtin_amdgcn_mfma_f32_16x16x32_bf16(afl[i], bfh[j], acc[i][j], 0, 0, 0);
            }
    }

#pragma unroll
    for (int j = 0; j < 4; ++j) {
        const int col = by * 128 + wn + 16 * j + rf;
        const float bias = bih[col] + bhh[col];
#pragma unroll
        for (int i = 0; i < 4; ++i) {
            const int row0 = bx * 128 + wm + 16 * i + bq * 4;
#pragma unroll
            for (int r = 0; r < 4; ++r)
                out[(size_t)(row0 + r) * HD + col] = acc[i][j][r] + bias;
        }
    }
}

// =====================================================================
// Phase B: recurrence — per-WAVE dataflow, drain-free spin.
//   Producer wave (b,w) owns flag slot flags[w*64+b] (packed dwords).
//   Consumer wave (b,w): lane l watches flags[w*64+l] -> ONE coalesced
//   dword load per poll covers all 64 producers; __all() resolves.
//   Spin happens when nothing is in flight (all drained before the
//   previous flag store) so its per-poll vmcnt(0) costs nothing.
//   Then: issue all h-loads -> xw prefetch -> MFMA (counted waits) ->
//   tanh -> h/io stores -> vmcnt(0) -> relaxed flag store.
// =====================================================================
__global__ void __launch_bounds__(256, 1) rnn_recurrence(
    const float* __restrict__ Whh,
    float* __restrict__ io,
    float* __restrict__ hn,
    unsigned short* __restrict__ hbuf,
    unsigned* __restrict__ flags)
{
    __shared__ unsigned short Whi[16][1032];
    __shared__ unsigned short Wlo[16][1032];

    const int tid = threadIdx.x;
    const int bx  = blockIdx.x;
    const int h0  = bx * 16;

    for (int i = tid; i < 16 * 1024; i += 256) {
        const int r = i >> 10, c = i & 1023;
        const float w = Whh[(size_t)(h0 + r) * HD + c];
        const unsigned short hi = f2bf(w);
        Whi[r][c] = hi;
        Wlo[r][c] = f2bf(w - bf2f(hi));
    }
    __syncthreads();   // only block-wide sync: W tiles ready

    const int lane = tid & 63, wid = tid >> 6;
    const int rf = lane & 15, bq = lane >> 4, kf = bq * 8;

    unsigned short* H0 = hbuf;             // buffer parity = producing step & 1
    unsigned short* H1 = hbuf + BA * HD;

    const int brow = wid * 16 + bq * 4;    // first of 4 batch rows this lane owns
    const int col  = h0 + rf;
    const int ab   = wid * 16 + rf;        // A-frag row (batch) for MFMA

    unsigned*       myflag = flags + wid * 64 + bx;
    const unsigned* watch  = flags + wid * 64 + lane;

    float v[4];
    unsigned hi4[4];
    float xwv[4];

    // ---- t = 0: h = tanh(xw_0); store H0 + io[0]; drain; flag = 1 ----
#pragma unroll
    for (int r = 0; r < 4; ++r) {
        v[r] = tanhf(io[(size_t)(brow + r) * HD + col]);
        hi4[r] = f2bf(v[r]);
    }
#pragma unroll
    for (int r = 0; r < 4; ++r) {
        const unsigned oh = __shfl_xor(hi4[r], 1);
        if ((lane & 1) == 0) {
            const size_t e = ((size_t)(brow + r) * HD + col) >> 1;
            __hip_atomic_store((unsigned*)H0 + e, (hi4[r] & 0xffffu) | (oh << 16),
                               __ATOMIC_RELAXED, __HIP_MEMORY_SCOPE_AGENT);
        }
        io[(size_t)(brow + r) * HD + col] = v[r];   // io[0] = h_0 (own tile)
    }
    waitcnt_vm0();
    if (lane == 0)
        __hip_atomic_store(myflag, 1u, __ATOMIC_RELAXED, __HIP_MEMORY_SCOPE_AGENT);

    // prefetch xw[1]
#pragma unroll
    for (int r = 0; r < 4; ++r)
        xwv[r] = io[(size_t)(BA * HD) + (size_t)(brow + r) * HD + col];

    for (int t = 1; t < SQ; ++t) {
        // ---- drain-free spin: one coalesced load per poll ----
        unsigned fv = __hip_atomic_load(watch, __ATOMIC_RELAXED, __HIP_MEMORY_SCOPE_AGENT);
        while (!__all((int)(fv >= (unsigned)t)))
            fv = __hip_atomic_load(watch, __ATOMIC_RELAXED, __HIP_MEMORY_SCOPE_AGENT);

        const unsigned short* Ph = (t & 1) ? H0 : H1;  // produced at step t-1
        unsigned short*       Nh = (t & 1) ? H1 : H0;  // produced at step t
        const unsigned short* ap = Ph + (size_t)ab * HD + kf;

        // issue ALL h-fragment loads first (compiler emits counted waits)
        short8 a[32];
#pragma unroll
        for (int kc = 0; kc < 32; ++kc)
            a[kc] = ld_frag(ap + (size_t)kc * 32);

        // then the xw[t+1] prefetch (completes under MFMA+tanh)
        float xwn[4] = {0.f, 0.f, 0.f, 0.f};
        if (t + 1 < SQ) {
            const float* nxt = io + (size_t)(t + 1) * (BA * HD);
#pragma unroll
            for (int r = 0; r < 4; ++r)
                xwn[r] = nxt[(size_t)(brow + r) * HD + col];
        }

        // 4 independent accumulator chains (hi/lo x even/odd kc)
        f32x4 ah0 = {}, ah1 = {}, al0 = {}, al1 = {};
#pragma unroll
        for (int kc = 0; kc < 32; ++kc) {
            short8 bh = *(const short8*)&Whi[rf][kc * 32 + kf];
            short8 bl = *(const short8*)&Wlo[rf][kc * 32 + kf];
            if (kc & 1) {
                ah1 = __builtin_amdgcn_mfma_f32_16x16x32_bf16(a[kc], bh, ah1, 0, 0, 0);
                al1 = __builtin_amdgcn_mfma_f32_16x16x32_bf16(a[kc], bl, al1, 0, 0, 0);
            } else {
                ah0 = __builtin_amdgcn_mfma_f32_16x16x32_bf16(a[kc], bh, ah0, 0, 0, 0);
                al0 = __builtin_amdgcn_mfma_f32_16x16x32_bf16(a[kc], bl, al0, 0, 0, 0);
            }
        }

#pragma unroll
        for (int r = 0; r < 4; ++r) {
            v[r] = tanhf(((ah0[r] + ah1[r]) + (al0[r] + al1[r])) + xwv[r]);
            hi4[r] = f2bf(v[r]);
            xwv[r] = xwn[r];
        }

        if (t < SQ - 1) {
            float* outP = io + (size_t)t * (BA * HD);
#pragma unroll
            for (int r = 0; r < 4; ++r) {
                const unsigned oh = __shfl_xor(hi4[r], 1);
                if ((lane & 1) == 0) {
                    const size_t e = ((size_t)(brow + r) * HD + col) >> 1;
                    __hip_atomic_store((unsigned*)Nh + e, (hi4[r] & 0xffffu) | (oh << 16),
                                       __ATOMIC_RELAXED, __HIP_MEMORY_SCOPE_AGENT);
                }
                outP[(size_t)(brow + r) * HD + col] = v[r];   // io[t] = h_t (own tile)
            }
            waitcnt_vm0();   // h-stores globally visible before epoch bump
            if (lane == 0)
                __hip_atomic_store(myflag, (unsigned)(t + 1),
                                   __ATOMIC_RELAXED, __HIP_MEMORY_SCOPE_AGENT);
        }
    }

    // epilogue: io[511] and h_n
    float* outL = io + (size_t)(SQ - 1) * (BA * HD);
#pragma unroll
    for (int r = 0; r < 4; ++r) {
        const size_t o = (size_t)(brow + r) * HD + col;
        outL[o] = v[r];
        hn[o]   = v[r];
    }
}

// =====================================================================
extern "C" void kernel_launch(void* const* d_in, const int* in_sizes, int n_in,
                              void* d_out, int out_size, void* d_ws, size_t ws_size,
                              hipStream_t stream) {
    const float* x   = (const float*)d_in[0];
    const float* Wih = (const float*)d_in[1];
    const float* Whh = (const float*)d_in[2];
    const float* bih = (const float*)d_in[3];
    const float* bhh = (const float*)d_in[4];

    float* io = (float*)d_out;                       // [512][64][1024]
    float* hn = io + (size_t)SQ * BA * HD;           // [1][64][1024]

    unsigned* flags = (unsigned*)d_ws;                             // 256 packed dwords
    unsigned short* hbuf = (unsigned short*)((char*)d_ws + 4096);  // 256 KB ping-pong

    hipLaunchKernelGGL(xw_gemm, dim3(256, 8), dim3(256), 0, stream,
                       x, Wih, bih, bhh, io, flags);

    void* args[] = {(void*)&Whh, (void*)&io, (void*)&hn, (void*)&hbuf, (void*)&flags};
    hipLaunchCooperativeKernel((void*)rnn_recurrence, dim3(NWG), dim3(256),
                               args, 0, stream);
}

// Round 3
// 5473.241 us; speedup vs baseline: 1.2979x; 1.0282x over previous
//
#include <hip/hip_runtime.h>

typedef short short8 __attribute__((ext_vector_type(8)));
typedef float f32x4 __attribute__((ext_vector_type(4)));
typedef unsigned short us4 __attribute__((ext_vector_type(4)));

#define SQ 512
#define BA 64
#define HD 1024
#define NWG 32        // 32 blocks x 32 output cols each

// ---------- bf16 helpers (round-to-nearest-even) ----------
__device__ __forceinline__ unsigned short f2bf(float f) {
    unsigned u = __float_as_uint(f);
    u += 0x7fffu + ((u >> 16) & 1u);
    return (unsigned short)(u >> 16);
}
__device__ __forceinline__ float bf2f(unsigned short h) {
    return __uint_as_float(((unsigned)h) << 16);
}
__device__ __forceinline__ void waitcnt_vm0() {
    asm volatile("s_waitcnt vmcnt(0)" ::: "memory");
}
// LLC-coherent 16-B fragment load as 2x8-B relaxed agent atomics
__device__ __forceinline__ short8 ld_frag(const unsigned short* p) {
    const unsigned long long* q = (const unsigned long long*)p;
    unsigned long long a = __hip_atomic_load(q,     __ATOMIC_RELAXED, __HIP_MEMORY_SCOPE_AGENT);
    unsigned long long b = __hip_atomic_load(q + 1, __ATOMIC_RELAXED, __HIP_MEMORY_SCOPE_AGENT);
    union { unsigned long long u[2]; short8 v; } cv;
    cv.u[0] = a; cv.u[1] = b;
    return cv.v;
}

// =====================================================================
// Phase A: xw = x @ W_ih^T + bias. Split-bf16, 3 MFMA products.
// Also zero-inits the 128 packed per-wave epoch flags (block (0,0)).
// =====================================================================
__global__ void __launch_bounds__(256) xw_gemm(
    const float* __restrict__ x, const float* __restrict__ Wih,
    const float* __restrict__ bih, const float* __restrict__ bhh,
    float* __restrict__ out, unsigned* __restrict__ flags)
{
    if (blockIdx.x == 0 && blockIdx.y == 0 && threadIdx.x < 128)
        flags[threadIdx.x] = 0u;   // 128 packed slots (4 wave-groups x 32 blocks)

    __shared__ unsigned short Ahi[128][40];
    __shared__ unsigned short Alo[128][40];
    __shared__ unsigned short Bhi[128][40];
    __shared__ unsigned short Blo[128][40];

    const int tid  = threadIdx.x;
    const int lane = tid & 63, wid = tid >> 6;
    const int bx = blockIdx.x, by = blockIdx.y;
    const int wm = (wid & 1) * 64, wn = (wid >> 1) * 64;
    const int rf = lane & 15, bq = lane >> 4, kf = bq * 8;

    f32x4 acc[4][4] = {};

    const int srow = tid >> 3;
    const int scol = (tid & 7) * 4;
    const float* aBase = x   + (size_t)(bx * 128 + srow) * HD + scol;
    const float* bBase = Wih + (size_t)(by * 128 + srow) * HD + scol;

    for (int kc = 0; kc < 32; ++kc) {
        __syncthreads();
        const int ko = kc * 32;
#pragma unroll
        for (int i = 0; i < 4; ++i) {
            const int r = srow + i * 32;
            float4 av = *(const float4*)(aBase + (size_t)(i * 32) * HD + ko);
            float4 bv = *(const float4*)(bBase + (size_t)(i * 32) * HD + ko);
            us4 ah, al, bh, bl;
            ah.x = f2bf(av.x); al.x = f2bf(av.x - bf2f(ah.x));
            ah.y = f2bf(av.y); al.y = f2bf(av.y - bf2f(ah.y));
            ah.z = f2bf(av.z); al.z = f2bf(av.z - bf2f(ah.z));
            ah.w = f2bf(av.w); al.w = f2bf(av.w - bf2f(ah.w));
            bh.x = f2bf(bv.x); bl.x = f2bf(bv.x - bf2f(bh.x));
            bh.y = f2bf(bv.y); bl.y = f2bf(bv.y - bf2f(bh.y));
            bh.z = f2bf(bv.z); bl.z = f2bf(bv.z - bf2f(bh.z));
            bh.w = f2bf(bv.w); bl.w = f2bf(bv.w - bf2f(bh.w));
            *(us4*)&Ahi[r][scol] = ah;
            *(us4*)&Alo[r][scol] = al;
            *(us4*)&Bhi[r][scol] = bh;
            *(us4*)&Blo[r][scol] = bl;
        }
        __syncthreads();

        short8 afh[4], afl[4], bfh[4], bfl[4];
#pragma unroll
        for (int i = 0; i < 4; ++i) {
            afh[i] = *(const short8*)&Ahi[wm + 16 * i + rf][kf];
            afl[i] = *(const short8*)&Alo[wm + 16 * i + rf][kf];
            bfh[i] = *(const short8*)&Bhi[wn + 16 * i + rf][kf];
            bfl[i] = *(const short8*)&Blo[wn + 16 * i + rf][kf];
        }
#pragma unroll
        for (int i = 0; i < 4; ++i)
#pragma unroll
            for (int j = 0; j < 4; ++j) {
                acc[i][j] = __builtin_amdgcn_mfma_f32_16x16x32_bf16(afh[i], bfh[j], acc[i][j], 0, 0, 0);
                acc[i][j] = __builtin_amdgcn_mfma_f32_16x16x32_bf16(afh[i], bfl[j], acc[i][j], 0, 0, 0);
                acc[i][j] = __builtin_amdgcn_mfma_f32_16x16x32_bf16(afl[i], bfh[j], acc[i][j], 0, 0, 0);
            }
    }

#pragma unroll
    for (int j = 0; j < 4; ++j) {
        const int col = by * 128 + wn + 16 * j + rf;
        const float bias = bih[col] + bhh[col];
#pragma unroll
        for (int i = 0; i < 4; ++i) {
            const int row0 = bx * 128 + wm + 16 * i + bq * 4;
#pragma unroll
            for (int r = 0; r < 4; ++r)
                out[(size_t)(row0 + r) * HD + col] = acc[i][j][r] + bias;
        }
    }
}

// =====================================================================
// Phase B: recurrence with 32 blocks (32 cols each), per-wave dataflow.
//   Wave (b,w) owns out tile [batch 16w..16w+16) x [cols 32b..32b+32).
//   Producer wave (b,w) owns flag flags[w*32+b]; consumer wave (b,w)
//   lane l watches flags[w*32+(l&31)] -> one 128-B line per poll.
//   Tail: pack/store h (8 dwords) -> vmcnt(0) -> flag=t+1 ->
//   io[t] stores + xw[t+1] prefetch (drained for free under next spin).
// =====================================================================
__global__ void __launch_bounds__(256, 1) rnn_recurrence(
    const float* __restrict__ Whh,
    float* __restrict__ io,
    float* __restrict__ hn,
    unsigned short* __restrict__ hbuf,
    unsigned* __restrict__ flags)
{
    __shared__ unsigned short Whi[32][1032];
    __shared__ unsigned short Wlo[32][1032];

    const int tid = threadIdx.x;
    const int bx  = blockIdx.x;
    const int h0  = bx * 32;

    for (int i = tid; i < 32 * 1024; i += 256) {
        const int r = i >> 10, c = i & 1023;
        const float w = Whh[(size_t)(h0 + r) * HD + c];
        const unsigned short hi = f2bf(w);
        Whi[r][c] = hi;
        Wlo[r][c] = f2bf(w - bf2f(hi));
    }
    __syncthreads();   // only block-wide sync: W tiles ready

    const int lane = tid & 63, wid = tid >> 6;
    const int rf = lane & 15, bq = lane >> 4, kf = bq * 8;

    unsigned short* H0 = hbuf;             // buffer parity = producing step & 1
    unsigned short* H1 = hbuf + BA * HD;

    const int brow = wid * 16 + bq * 4;    // first of 4 batch rows this lane owns
    const int ab   = wid * 16 + rf;        // A-frag row (batch) for MFMA
    const int col0 = h0 + rf;              // N-tile j column: col0 + 16*j

    unsigned*       myflag = flags + wid * 32 + bx;
    const unsigned* watch  = flags + wid * 32 + (lane & 31);

    float v[2][4];
    unsigned hi4[2][4];
    float xwv[2][4];

    // ---- t = 0: h = tanh(xw_0); store H0; drain; flag=1; io[0]+xw[1] ----
#pragma unroll
    for (int j = 0; j < 2; ++j)
#pragma unroll
        for (int r = 0; r < 4; ++r) {
            v[j][r] = tanhf(io[(size_t)(brow + r) * HD + col0 + 16 * j]);
            hi4[j][r] = f2bf(v[j][r]);
        }
#pragma unroll
    for (int j = 0; j < 2; ++j)
#pragma unroll
        for (int r = 0; r < 4; ++r) {
            const unsigned oh = __shfl_xor(hi4[j][r], 1);
            if ((lane & 1) == 0) {
                const size_t e = ((size_t)(brow + r) * HD + col0 + 16 * j) >> 1;
                __hip_atomic_store((unsigned*)H0 + e, (hi4[j][r] & 0xffffu) | (oh << 16),
                                   __ATOMIC_RELAXED, __HIP_MEMORY_SCOPE_AGENT);
            }
        }
    waitcnt_vm0();
    if (lane == 0)
        __hip_atomic_store(myflag, 1u, __ATOMIC_RELAXED, __HIP_MEMORY_SCOPE_AGENT);

    // off critical path: io[0] = h_0 (own tile) and xw[1] prefetch
#pragma unroll
    for (int j = 0; j < 2; ++j)
#pragma unroll
        for (int r = 0; r < 4; ++r)
            io[(size_t)(brow + r) * HD + col0 + 16 * j] = v[j][r];
#pragma unroll
    for (int j = 0; j < 2; ++j)
#pragma unroll
        for (int r = 0; r < 4; ++r)
            xwv[j][r] = io[(size_t)(BA * HD) + (size_t)(brow + r) * HD + col0 + 16 * j];

    for (int t = 1; t < SQ; ++t) {
        // ---- spin: one 128-B line per poll, s_sleep backoff ----
        unsigned fv = __hip_atomic_load(watch, __ATOMIC_RELAXED, __HIP_MEMORY_SCOPE_AGENT);
        while (!__all((int)(fv >= (unsigned)t))) {
            __builtin_amdgcn_s_sleep(1);
            fv = __hip_atomic_load(watch, __ATOMIC_RELAXED, __HIP_MEMORY_SCOPE_AGENT);
        }

        const unsigned short* Ph = (t & 1) ? H0 : H1;  // produced at step t-1
        unsigned short*       Nh = (t & 1) ? H1 : H0;  // produced at step t
        const unsigned short* ap = Ph + (size_t)ab * HD + kf;

        // issue ALL h-fragment loads (compiler emits counted waits)
        short8 a[32];
#pragma unroll
        for (int kc = 0; kc < 32; ++kc)
            a[kc] = ld_frag(ap + (size_t)kc * 32);

        // 8 independent accumulator chains: 2 N-tiles x hi/lo x even/odd kc
        f32x4 c0h0 = {}, c0h1 = {}, c0l0 = {}, c0l1 = {};
        f32x4 c1h0 = {}, c1h1 = {}, c1l0 = {}, c1l1 = {};
#pragma unroll
        for (int kc = 0; kc < 32; ++kc) {
            short8 b0h = *(const short8*)&Whi[rf][kc * 32 + kf];
            short8 b0l = *(const short8*)&Wlo[rf][kc * 32 + kf];
            short8 b1h = *(const short8*)&Whi[16 + rf][kc * 32 + kf];
            short8 b1l = *(const short8*)&Wlo[16 + rf][kc * 32 + kf];
            if (kc & 1) {
                c0h1 = __builtin_amdgcn_mfma_f32_16x16x32_bf16(a[kc], b0h, c0h1, 0, 0, 0);
                c0l1 = __builtin_amdgcn_mfma_f32_16x16x32_bf16(a[kc], b0l, c0l1, 0, 0, 0);
                c1h1 = __builtin_amdgcn_mfma_f32_16x16x32_bf16(a[kc], b1h, c1h1, 0, 0, 0);
                c1l1 = __builtin_amdgcn_mfma_f32_16x16x32_bf16(a[kc], b1l, c1l1, 0, 0, 0);
            } else {
                c0h0 = __builtin_amdgcn_mfma_f32_16x16x32_bf16(a[kc], b0h, c0h0, 0, 0, 0);
                c0l0 = __builtin_amdgcn_mfma_f32_16x16x32_bf16(a[kc], b0l, c0l0, 0, 0, 0);
                c1h0 = __builtin_amdgcn_mfma_f32_16x16x32_bf16(a[kc], b1h, c1h0, 0, 0, 0);
                c1l0 = __builtin_amdgcn_mfma_f32_16x16x32_bf16(a[kc], b1l, c1l0, 0, 0, 0);
            }
        }

#pragma unroll
        for (int r = 0; r < 4; ++r) {
            v[0][r] = tanhf(((c0h0[r] + c0h1[r]) + (c0l0[r] + c0l1[r])) + xwv[0][r]);
            v[1][r] = tanhf(((c1h0[r] + c1h1[r]) + (c1l0[r] + c1l1[r])) + xwv[1][r]);
            hi4[0][r] = f2bf(v[0][r]);
            hi4[1][r] = f2bf(v[1][r]);
        }

        if (t < SQ - 1) {
            // critical path: h stores -> drain -> flag
#pragma unroll
            for (int j = 0; j < 2; ++j)
#pragma unroll
                for (int r = 0; r < 4; ++r) {
                    const unsigned oh = __shfl_xor(hi4[j][r], 1);
                    if ((lane & 1) == 0) {
                        const size_t e = ((size_t)(brow + r) * HD + col0 + 16 * j) >> 1;
                        __hip_atomic_store((unsigned*)Nh + e, (hi4[j][r] & 0xffffu) | (oh << 16),
                                           __ATOMIC_RELAXED, __HIP_MEMORY_SCOPE_AGENT);
                    }
                }
            waitcnt_vm0();   // h-stores globally visible before epoch bump
            if (lane == 0)
                __hip_atomic_store(myflag, (unsigned)(t + 1),
                                   __ATOMIC_RELAXED, __HIP_MEMORY_SCOPE_AGENT);

            // off critical path: io[t] = h_t (own tile) and xw[t+1] prefetch
            float* outP = io + (size_t)t * (BA * HD);
            const float* nxt = io + (size_t)(t + 1) * (BA * HD);
#pragma unroll
            for (int j = 0; j < 2; ++j)
#pragma unroll
                for (int r = 0; r < 4; ++r) {
                    outP[(size_t)(brow + r) * HD + col0 + 16 * j] = v[j][r];
                    xwv[j][r] = nxt[(size_t)(brow + r) * HD + col0 + 16 * j];
                }
        }
    }

    // epilogue: io[511] and h_n
    float* outL = io + (size_t)(SQ - 1) * (BA * HD);
#pragma unroll
    for (int j = 0; j < 2; ++j)
#pragma unroll
        for (int r = 0; r < 4; ++r) {
            const size_t o = (size_t)(brow + r) * HD + col0 + 16 * j;
            outL[o] = v[j][r];
            hn[o]   = v[j][r];
        }
}

// =====================================================================
extern "C" void kernel_launch(void* const* d_in, const int* in_sizes, int n_in,
                              void* d_out, int out_size, void* d_ws, size_t ws_size,
                              hipStream_t stream) {
    const float* x   = (const float*)d_in[0];
    const float* Wih = (const float*)d_in[1];
    const float* Whh = (const float*)d_in[2];
    const float* bih = (const float*)d_in[3];
    const float* bhh = (const float*)d_in[4];

    float* io = (float*)d_out;                       // [512][64][1024]
    float* hn = io + (size_t)SQ * BA * HD;           // [1][64][1024]

    unsigned* flags = (unsigned*)d_ws;                             // 128 packed dwords
    unsigned short* hbuf = (unsigned short*)((char*)d_ws + 4096);  // 256 KB ping-pong

    hipLaunchKernelGGL(xw_gemm, dim3(256, 8), dim3(256), 0, stream,
                       x, Wih, bih, bhh, io, flags);

    void* args[] = {(void*)&Whh, (void*)&io, (void*)&hn, (void*)&hbuf, (void*)&flags};
    hipLaunchCooperativeKernel((void*)rnn_recurrence, dim3(NWG), dim3(256),
                               args, 0, stream);
}

// Round 7
// 5450.113 us; speedup vs baseline: 1.3034x; 1.0042x over previous
//
#include <hip/hip_runtime.h>

typedef short short8 __attribute__((ext_vector_type(8)));
typedef float f32x4 __attribute__((ext_vector_type(4)));
typedef unsigned short us4 __attribute__((ext_vector_type(4)));

#define SQ 512
#define BA 64
#define HD 1024
#define NWG 32        // 32 blocks x 32 output cols each

// ---------- bf16 helpers (round-to-nearest-even) ----------
__device__ __forceinline__ unsigned short f2bf(float f) {
    unsigned u = __float_as_uint(f);
    u += 0x7fffu + ((u >> 16) & 1u);
    return (unsigned short)(u >> 16);
}
__device__ __forceinline__ float bf2f(unsigned short h) {
    return __uint_as_float(((unsigned)h) << 16);
}
__device__ __forceinline__ void waitcnt_vm0() {
    asm volatile("s_waitcnt vmcnt(0)" ::: "memory");
}
// LLC-coherent 16-B fragment load as 2x8-B relaxed agent atomics
__device__ __forceinline__ short8 ld_frag(const unsigned short* p) {
    const unsigned long long* q = (const unsigned long long*)p;
    unsigned long long a = __hip_atomic_load(q,     __ATOMIC_RELAXED, __HIP_MEMORY_SCOPE_AGENT);
    unsigned long long b = __hip_atomic_load(q + 1, __ATOMIC_RELAXED, __HIP_MEMORY_SCOPE_AGENT);
    union { unsigned long long u[2]; short8 v; } cv;
    cv.u[0] = a; cv.u[1] = b;
    return cv.v;
}

// =====================================================================
// Phase A: xw = x @ W_ih^T + bias. Split-bf16, 3 MFMA products.
// Also zero-inits the 128 packed per-wave epoch flags (block (0,0)).
// =====================================================================
__global__ void __launch_bounds__(256) xw_gemm(
    const float* __restrict__ x, const float* __restrict__ Wih,
    const float* __restrict__ bih, const float* __restrict__ bhh,
    float* __restrict__ out, unsigned* __restrict__ flags)
{
    if (blockIdx.x == 0 && blockIdx.y == 0 && threadIdx.x < 128)
        flags[threadIdx.x] = 0u;   // 128 packed slots (4 wave-groups x 32 blocks)

    __shared__ unsigned short Ahi[128][40];
    __shared__ unsigned short Alo[128][40];
    __shared__ unsigned short Bhi[128][40];
    __shared__ unsigned short Blo[128][40];

    const int tid  = threadIdx.x;
    const int lane = tid & 63, wid = tid >> 6;
    const int bx = blockIdx.x, by = blockIdx.y;
    const int wm = (wid & 1) * 64, wn = (wid >> 1) * 64;
    const int rf = lane & 15, bq = lane >> 4, kf = bq * 8;

    f32x4 acc[4][4] = {};

    const int srow = tid >> 3;
    const int scol = (tid & 7) * 4;
    const float* aBase = x   + (size_t)(bx * 128 + srow) * HD + scol;
    const float* bBase = Wih + (size_t)(by * 128 + srow) * HD + scol;

    for (int kc = 0; kc < 32; ++kc) {
        __syncthreads();
        const int ko = kc * 32;
#pragma unroll
        for (int i = 0; i < 4; ++i) {
            const int r = srow + i * 32;
            float4 av = *(const float4*)(aBase + (size_t)(i * 32) * HD + ko);
            float4 bv = *(const float4*)(bBase + (size_t)(i * 32) * HD + ko);
            us4 ah, al, bh, bl;
            ah.x = f2bf(av.x); al.x = f2bf(av.x - bf2f(ah.x));
            ah.y = f2bf(av.y); al.y = f2bf(av.y - bf2f(ah.y));
            ah.z = f2bf(av.z); al.z = f2bf(av.z - bf2f(ah.z));
            ah.w = f2bf(av.w); al.w = f2bf(av.w - bf2f(ah.w));
            bh.x = f2bf(bv.x); bl.x = f2bf(bv.x - bf2f(bh.x));
            bh.y = f2bf(bv.y); bl.y = f2bf(bv.y - bf2f(bh.y));
            bh.z = f2bf(bv.z); bl.z = f2bf(bv.z - bf2f(bh.z));
            bh.w = f2bf(bv.w); bl.w = f2bf(bv.w - bf2f(bh.w));
            *(us4*)&Ahi[r][scol] = ah;
            *(us4*)&Alo[r][scol] = al;
            *(us4*)&Bhi[r][scol] = bh;
            *(us4*)&Blo[r][scol] = bl;
        }
        __syncthreads();

        short8 afh[4], afl[4], bfh[4], bfl[4];
#pragma unroll
        for (int i = 0; i < 4; ++i) {
            afh[i] = *(const short8*)&Ahi[wm + 16 * i + rf][kf];
            afl[i] = *(const short8*)&Alo[wm + 16 * i + rf][kf];
            bfh[i] = *(const short8*)&Bhi[wn + 16 * i + rf][kf];
            bfl[i] = *(const short8*)&Blo[wn + 16 * i + rf][kf];
        }
#pragma unroll
        for (int i = 0; i < 4; ++i)
#pragma unroll
            for (int j = 0; j < 4; ++j) {
                acc[i][j] = __builtin_amdgcn_mfma_f32_16x16x32_bf16(afh[i], bfh[j], acc[i][j], 0, 0, 0);
                acc[i][j] = __builtin_amdgcn_mfma_f32_16x16x32_bf16(afh[i], bfl[j], acc[i][j], 0, 0, 0);
                acc[i][j] = __builtin_amdgcn_mfma_f32_16x16x32_bf16(afl[i], bfh[j], acc[i][j], 0, 0, 0);
            }
    }

#pragma unroll
    for (int j = 0; j < 4; ++j) {
        const int col = by * 128 + wn + 16 * j + rf;
        const float bias = bih[col] + bhh[col];
#pragma unroll
        for (int i = 0; i < 4; ++i) {
            const int row0 = bx * 128 + wm + 16 * i + bq * 4;
#pragma unroll
            for (int r = 0; r < 4; ++r)
                out[(size_t)(row0 + r) * HD + col] = acc[i][j][r] + bias;
        }
    }
}

// =====================================================================
// Phase B: recurrence with 32 blocks (32 cols each), per-wave dataflow.
//   Identical to the verified R3 kernel EXCEPT one change: a compiler
//   scheduling fence (empty asm w/ memory clobber) between the 32
//   fragment-load issues and the MFMA loop. R3's VGPR_Count=132 proved
//   the compiler sank the loads into the MFMA loop (~8 serial LLC RTs
//   per step = the 9-10us/step floor). The fence forces all 64 8-B
//   atomic loads to issue before any use -> one pipelined LLC RT; the
//   batch (128 VGPRs) fits the 512-VGPR budget at launch_bounds(256,1).
// =====================================================================
__global__ void __launch_bounds__(256, 1) rnn_recurrence(
    const float* __restrict__ Whh,
    float* __restrict__ io,
    float* __restrict__ hn,
    unsigned short* __restrict__ hbuf,
    unsigned* __restrict__ flags)
{
    __shared__ unsigned short Whi[32][1032];
    __shared__ unsigned short Wlo[32][1032];

    const int tid = threadIdx.x;
    const int bx  = blockIdx.x;
    const int h0  = bx * 32;

    for (int i = tid; i < 32 * 1024; i += 256) {
        const int r = i >> 10, c = i & 1023;
        const float w = Whh[(size_t)(h0 + r) * HD + c];
        const unsigned short hi = f2bf(w);
        Whi[r][c] = hi;
        Wlo[r][c] = f2bf(w - bf2f(hi));
    }
    __syncthreads();   // only block-wide sync: W tiles ready

    const int lane = tid & 63, wid = tid >> 6;
    const int rf = lane & 15, bq = lane >> 4, kf = bq * 8;

    unsigned short* H0 = hbuf;             // buffer parity = producing step & 1
    unsigned short* H1 = hbuf + BA * HD;

    const int brow = wid * 16 + bq * 4;    // first of 4 batch rows this lane owns
    const int ab   = wid * 16 + rf;        // A-frag row (batch) for MFMA
    const int col0 = h0 + rf;              // N-tile j column: col0 + 16*j

    unsigned*       myflag = flags + wid * 32 + bx;
    const unsigned* watch  = flags + wid * 32 + (lane & 31);

    float v[2][4];
    unsigned hi4[2][4];
    float xwv[2][4];

    // ---- t = 0: h = tanh(xw_0); store H0; drain; flag=1; io[0]+xw[1] ----
#pragma unroll
    for (int j = 0; j < 2; ++j)
#pragma unroll
        for (int r = 0; r < 4; ++r) {
            v[j][r] = tanhf(io[(size_t)(brow + r) * HD + col0 + 16 * j]);
            hi4[j][r] = f2bf(v[j][r]);
        }
#pragma unroll
    for (int j = 0; j < 2; ++j)
#pragma unroll
        for (int r = 0; r < 4; ++r) {
            const unsigned oh = __shfl_xor(hi4[j][r], 1);
            if ((lane & 1) == 0) {
                const size_t e = ((size_t)(brow + r) * HD + col0 + 16 * j) >> 1;
                __hip_atomic_store((unsigned*)H0 + e, (hi4[j][r] & 0xffffu) | (oh << 16),
                                   __ATOMIC_RELAXED, __HIP_MEMORY_SCOPE_AGENT);
            }
        }
    waitcnt_vm0();
    if (lane == 0)
        __hip_atomic_store(myflag, 1u, __ATOMIC_RELAXED, __HIP_MEMORY_SCOPE_AGENT);

    // off critical path: io[0] = h_0 (own tile) and xw[1] prefetch
#pragma unroll
    for (int j = 0; j < 2; ++j)
#pragma unroll
        for (int r = 0; r < 4; ++r)
            io[(size_t)(brow + r) * HD + col0 + 16 * j] = v[j][r];
#pragma unroll
    for (int j = 0; j < 2; ++j)
#pragma unroll
        for (int r = 0; r < 4; ++r)
            xwv[j][r] = io[(size_t)(BA * HD) + (size_t)(brow + r) * HD + col0 + 16 * j];

    for (int t = 1; t < SQ; ++t) {
        // ---- spin: one 128-B line per poll, s_sleep backoff ----
        unsigned fv = __hip_atomic_load(watch, __ATOMIC_RELAXED, __HIP_MEMORY_SCOPE_AGENT);
        while (!__all((int)(fv >= (unsigned)t))) {
            __builtin_amdgcn_s_sleep(1);
            fv = __hip_atomic_load(watch, __ATOMIC_RELAXED, __HIP_MEMORY_SCOPE_AGENT);
        }

        const unsigned short* Ph = (t & 1) ? H0 : H1;  // produced at step t-1
        unsigned short*       Nh = (t & 1) ? H1 : H0;  // produced at step t
        const unsigned short* ap = Ph + (size_t)ab * HD + kf;

        // issue ALL h-fragment loads...
        short8 a[32];
#pragma unroll
        for (int kc = 0; kc < 32; ++kc)
            a[kc] = ld_frag(ap + (size_t)kc * 32);

        // ...and PIN them before any use: atomic loads cannot cross a
        // memory-clobber asm, so all 64 dwordx2 issue back-to-back and
        // the whole batch drains in ~one pipelined LLC round trip.
        asm volatile("" ::: "memory");

        // 8 independent accumulator chains: 2 N-tiles x hi/lo x even/odd kc
        f32x4 c0h0 = {}, c0h1 = {}, c0l0 = {}, c0l1 = {};
        f32x4 c1h0 = {}, c1h1 = {}, c1l0 = {}, c1l1 = {};
#pragma unroll
        for (int kc = 0; kc < 32; ++kc) {
            short8 b0h = *(const short8*)&Whi[rf][kc * 32 + kf];
            short8 b0l = *(const short8*)&Wlo[rf][kc * 32 + kf];
            short8 b1h = *(const short8*)&Whi[16 + rf][kc * 32 + kf];
            short8 b1l = *(const short8*)&Wlo[16 + rf][kc * 32 + kf];
            if (kc & 1) {
                c0h1 = __builtin_amdgcn_mfma_f32_16x16x32_bf16(a[kc], b0h, c0h1, 0, 0, 0);
                c0l1 = __builtin_amdgcn_mfma_f32_16x16x32_bf16(a[kc], b0l, c0l1, 0, 0, 0);
                c1h1 = __builtin_amdgcn_mfma_f32_16x16x32_bf16(a[kc], b1h, c1h1, 0, 0, 0);
                c1l1 = __builtin_amdgcn_mfma_f32_16x16x32_bf16(a[kc], b1l, c1l1, 0, 0, 0);
            } else {
                c0h0 = __builtin_amdgcn_mfma_f32_16x16x32_bf16(a[kc], b0h, c0h0, 0, 0, 0);
                c0l0 = __builtin_amdgcn_mfma_f32_16x16x32_bf16(a[kc], b0l, c0l0, 0, 0, 0);
                c1h0 = __builtin_amdgcn_mfma_f32_16x16x32_bf16(a[kc], b1h, c1h0, 0, 0, 0);
                c1l0 = __builtin_amdgcn_mfma_f32_16x16x32_bf16(a[kc], b1l, c1l0, 0, 0, 0);
            }
        }

#pragma unroll
        for (int r = 0; r < 4; ++r) {
            v[0][r] = tanhf(((c0h0[r] + c0h1[r]) + (c0l0[r] + c0l1[r])) + xwv[0][r]);
            v[1][r] = tanhf(((c1h0[r] + c1h1[r]) + (c1l0[r] + c1l1[r])) + xwv[1][r]);
            hi4[0][r] = f2bf(v[0][r]);
            hi4[1][r] = f2bf(v[1][r]);
        }

        if (t < SQ - 1) {
            // critical path: h stores -> drain -> flag
#pragma unroll
            for (int j = 0; j < 2; ++j)
#pragma unroll
                for (int r = 0; r < 4; ++r) {
                    const unsigned oh = __shfl_xor(hi4[j][r], 1);
                    if ((lane & 1) == 0) {
                        const size_t e = ((size_t)(brow + r) * HD + col0 + 16 * j) >> 1;
                        __hip_atomic_store((unsigned*)Nh + e, (hi4[j][r] & 0xffffu) | (oh << 16),
                                           __ATOMIC_RELAXED, __HIP_MEMORY_SCOPE_AGENT);
                    }
                }
            waitcnt_vm0();   // h-stores globally visible before epoch bump
            if (lane == 0)
                __hip_atomic_store(myflag, (unsigned)(t + 1),
                                   __ATOMIC_RELAXED, __HIP_MEMORY_SCOPE_AGENT);

            // off critical path: io[t] = h_t (own tile) and xw[t+1] prefetch
            float* outP = io + (size_t)t * (BA * HD);
            const float* nxt = io + (size_t)(t + 1) * (BA * HD);
#pragma unroll
            for (int j = 0; j < 2; ++j)
#pragma unroll
                for (int r = 0; r < 4; ++r) {
                    outP[(size_t)(brow + r) * HD + col0 + 16 * j] = v[j][r];
                    xwv[j][r] = nxt[(size_t)(brow + r) * HD + col0 + 16 * j];
                }
        }
    }

    // epilogue: io[511] and h_n
    float* outL = io + (size_t)(SQ - 1) * (BA * HD);
#pragma unroll
    for (int j = 0; j < 2; ++j)
#pragma unroll
        for (int r = 0; r < 4; ++r) {
            const size_t o = (size_t)(brow + r) * HD + col0 + 16 * j;
            outL[o] = v[j][r];
            hn[o]   = v[j][r];
        }
}

// =====================================================================
extern "C" void kernel_launch(void* const* d_in, const int* in_sizes, int n_in,
                              void* d_out, int out_size, void* d_ws, size_t ws_size,
                              hipStream_t stream) {
    const float* x   = (const float*)d_in[0];
    const float* Wih = (const float*)d_in[1];
    const float* Whh = (const float*)d_in[2];
    const float* bih = (const float*)d_in[3];
    const float* bhh = (const float*)d_in[4];

    float* io = (float*)d_out;                       // [512][64][1024]
    float* hn = io + (size_t)SQ * BA * HD;           // [1][64][1024]

    unsigned* flags = (unsigned*)d_ws;                             // 128 packed dwords
    unsigned short* hbuf = (unsigned short*)((char*)d_ws + 4096);  // 256 KB ping-pong

    hipLaunchKernelGGL(xw_gemm, dim3(256, 8), dim3(256), 0, stream,
                       x, Wih, bih, bhh, io, flags);

    void* args[] = {(void*)&Whh, (void*)&io, (void*)&hn, (void*)&hbuf, (void*)&flags};
    hipLaunchCooperativeKernel((void*)rnn_recurrence, dim3(NWG), dim3(256),
                               args, 0, stream);
}